// Round 1
// baseline (132.059 us; speedup 1.0000x reference)
//
#include <hip/hip_runtime.h>
#include <hip/hip_bf16.h>

// ---- problem constants ----
#define NBATCH   16
#define SIGLEN   240000
#define FRAMES   1197                 // (240000-800)/200 + 1
#define M_TOTAL  (NBATCH * FRAMES)    // 19152
#define K_TOTAL  800
#define NBINS    401
#define NOUT     (2 * NBINS)          // 802, interleaved re/im
#define FSTEP    200

// ---- GEMM tiling ----
#define BM 128
#define BN 128
#define BK 32
#define LDSS 40                        // padded LDS row stride (bf16 elems): 80B/row -> ~2-way bank alias (free)
#define NTILES_N 7                     // ceil(802/128)
#define NTILES_M ((M_TOTAL + BM - 1) / BM)   // 150

typedef float  f32x4  __attribute__((ext_vector_type(4)));
typedef __bf16 bf16x8 __attribute__((ext_vector_type(8)));

static __device__ __forceinline__ unsigned f2bf_pair(float lo, float hi) {
    // RNE f32->bf16, packed pair
    union { float f; unsigned u; } a, b;
    a.f = lo; b.f = hi;
    unsigned ua = (a.u + 0x7fffu + ((a.u >> 16) & 1u)) >> 16;
    unsigned ub = (b.u + 0x7fffu + ((b.u >> 16) & 1u)) >> 16;
    return ua | (ub << 16);
}

__global__ __launch_bounds__(256) void stft_gemm(
    const float* __restrict__ sig, const float* __restrict__ wnd,
    const float* __restrict__ dcos, const float* __restrict__ dsin,
    float* __restrict__ out)
{
    __shared__ ushort As[BM * LDSS];
    __shared__ ushort Bs[BN * LDSS];
    __shared__ int rowBase[BM];

    const int tid = threadIdx.x;
    const int bid = blockIdx.x;
    const int mt  = bid / NTILES_N;
    const int nt  = bid - mt * NTILES_N;
    const int m0  = mt * BM;
    const int j0  = nt * BN;

    // per-row signal base offsets (frame gather), once per block
    if (tid < BM) {
        int m = m0 + tid;
        int v = -1;
        if (m < M_TOTAL) {
            int b  = m / FRAMES;
            int fl = m - b * FRAMES;
            v = b * SIGLEN + fl * FSTEP;
        }
        rowBase[tid] = v;
    }

    // staging assignment: 2 threads per tile row, 16 f32 each
    const int rS = tid >> 1;
    const int hS = tid & 1;

    // B source row for this thread (fixed across K-steps)
    const float* bRow = nullptr;
    {
        int j = j0 + rS;
        if (j < NOUT) {
            const float* srcm = (j & 1) ? dsin : dcos;
            bRow = srcm + (size_t)(j >> 1) * K_TOTAL;
        }
    }

    const int lane = tid & 63;
    const int wave = tid >> 6;
    const int wm   = wave >> 1;
    const int wn   = wave & 1;
    const int lr   = lane & 15;   // row (A) / col (B/C)
    const int lg   = lane >> 4;   // k-group

    f32x4 acc[4][4];
    #pragma unroll
    for (int i = 0; i < 4; ++i)
        #pragma unroll
        for (int jj = 0; jj < 4; ++jj)
            acc[i][jj] = (f32x4){0.f, 0.f, 0.f, 0.f};

    __syncthreads();   // rowBase ready

    for (int k0 = 0; k0 < K_TOTAL; k0 += BK) {
        // ---- stage A: gather signal, window, convert bf16 ----
        {
            int base = rowBase[rS];
            float4 f0, f1, f2, f3;
            if (base >= 0) {
                const float4* sp = (const float4*)(sig + base + k0 + hS * 16);
                f0 = sp[0]; f1 = sp[1]; f2 = sp[2]; f3 = sp[3];
            } else {
                f0 = make_float4(0.f,0.f,0.f,0.f); f1 = f0; f2 = f0; f3 = f0;
            }
            const float4* wp = (const float4*)(wnd + k0 + hS * 16);
            float4 w0 = wp[0], w1 = wp[1], w2 = wp[2], w3 = wp[3];
            uint4 p0, p1;
            p0.x = f2bf_pair(f0.x * w0.x, f0.y * w0.y);
            p0.y = f2bf_pair(f0.z * w0.z, f0.w * w0.w);
            p0.z = f2bf_pair(f1.x * w1.x, f1.y * w1.y);
            p0.w = f2bf_pair(f1.z * w1.z, f1.w * w1.w);
            p1.x = f2bf_pair(f2.x * w2.x, f2.y * w2.y);
            p1.y = f2bf_pair(f2.z * w2.z, f2.w * w2.w);
            p1.z = f2bf_pair(f3.x * w3.x, f3.y * w3.y);
            p1.w = f2bf_pair(f3.z * w3.z, f3.w * w3.w);
            uint4* dst = (uint4*)&As[rS * LDSS + hS * 16];
            dst[0] = p0;
            dst[1] = p1;
        }
        // ---- stage B: DFT rows (cos/sin interleaved by column parity) ----
        {
            uint4 p0, p1;
            if (bRow) {
                const float4* sp = (const float4*)(bRow + k0 + hS * 16);
                float4 f0 = sp[0], f1 = sp[1], f2 = sp[2], f3 = sp[3];
                p0.x = f2bf_pair(f0.x, f0.y);
                p0.y = f2bf_pair(f0.z, f0.w);
                p0.z = f2bf_pair(f1.x, f1.y);
                p0.w = f2bf_pair(f1.z, f1.w);
                p1.x = f2bf_pair(f2.x, f2.y);
                p1.y = f2bf_pair(f2.z, f2.w);
                p1.z = f2bf_pair(f3.x, f3.y);
                p1.w = f2bf_pair(f3.z, f3.w);
            } else {
                p0 = make_uint4(0u,0u,0u,0u);
                p1 = p0;
            }
            uint4* dst = (uint4*)&Bs[rS * LDSS + hS * 16];
            dst[0] = p0;
            dst[1] = p1;
        }
        __syncthreads();

        // ---- fragments + MFMA ----
        bf16x8 a[4], b[4];
        #pragma unroll
        for (int i = 0; i < 4; ++i)
            a[i] = *(const bf16x8*)&As[(wm * 64 + i * 16 + lr) * LDSS + lg * 8];
        #pragma unroll
        for (int i = 0; i < 4; ++i)
            b[i] = *(const bf16x8*)&Bs[(wn * 64 + i * 16 + lr) * LDSS + lg * 8];
        #pragma unroll
        for (int i = 0; i < 4; ++i)
            #pragma unroll
            for (int jj = 0; jj < 4; ++jj)
                acc[i][jj] = __builtin_amdgcn_mfma_f32_16x16x32_bf16(a[i], b[jj], acc[i][jj], 0, 0, 0);

        __syncthreads();
    }

    // ---- epilogue: C/D layout col=lane&15, row=4*(lane>>4)+reg ----
    const int mb = m0 + wm * 64;
    const int jb = j0 + wn * 64;
    #pragma unroll
    for (int i = 0; i < 4; ++i) {
        #pragma unroll
        for (int jj = 0; jj < 4; ++jj) {
            int col = jb + jj * 16 + lr;
            if (col >= NOUT) continue;
            #pragma unroll
            for (int r = 0; r < 4; ++r) {
                int row = mb + i * 16 + lg * 4 + r;
                if (row < M_TOTAL)
                    out[(size_t)row * NOUT + col] = acc[i][jj][r];
            }
        }
    }
}

extern "C" void kernel_launch(void* const* d_in, const int* in_sizes, int n_in,
                              void* d_out, int out_size, void* d_ws, size_t ws_size,
                              hipStream_t stream) {
    const float* sig  = (const float*)d_in[0];
    const float* wnd  = (const float*)d_in[1];
    const float* dcos = (const float*)d_in[2];
    const float* dsin = (const float*)d_in[3];
    float* out = (float*)d_out;

    dim3 grid(NTILES_M * NTILES_N);
    dim3 block(256);
    stft_gemm<<<grid, block, 0, stream>>>(sig, wnd, dcos, dsin, out);
}

// Round 2
// 82.550 us; speedup vs baseline: 1.5997x; 1.5997x over previous
//
#include <hip/hip_runtime.h>
#include <hip/hip_bf16.h>

// ---- problem constants ----
#define NBATCH   16
#define SIGLEN   240000
#define FRAMES   1197                 // (240000-800)/200 + 1
#define M_TOTAL  (NBATCH * FRAMES)    // 19152
#define K_TOTAL  800
#define NBINS    401
#define NOUT     (2 * NBINS)          // 802, interleaved re/im
#define FSTEP    200

// ---- GEMM tiling ----
#define BM 128
#define BN 128
#define BK 32
#define NTILES_N 7                    // ceil(802/128)
#define NTILES_M 150                  // ceil(19152/128)
#define NWG      (NTILES_M * NTILES_N) // 1050
#define M_PAD    (NTILES_M * BM)      // 19200
#define N_PAD    (NTILES_N * BN)      // 896

#define A_WS_ELEMS ((size_t)M_PAD * K_TOTAL)          // bf16 elems
#define B_WS_ELEMS ((size_t)N_PAD * K_TOTAL)
#define WS_NEEDED  ((A_WS_ELEMS + B_WS_ELEMS) * 2)    // 32,153,600 B

typedef float  f32x4  __attribute__((ext_vector_type(4)));
typedef __bf16 bf16x8 __attribute__((ext_vector_type(8)));

static __device__ __forceinline__ unsigned f2bf_pair(float lo, float hi) {
    // RNE f32->bf16, packed pair
    union { float f; unsigned u; } a, b;
    a.f = lo; b.f = hi;
    unsigned ua = (a.u + 0x7fffu + ((a.u >> 16) & 1u)) >> 16;
    unsigned ub = (b.u + 0x7fffu + ((b.u >> 16) & 1u)) >> 16;
    return ua | (ub << 16);
}

static __device__ __forceinline__ void gload_lds16(const void* g, void* l) {
    // async global->LDS, 16B per lane; LDS dest = wave-uniform base + lane*16
    __builtin_amdgcn_global_load_lds(
        (const __attribute__((address_space(1))) void*)g,
        (__attribute__((address_space(3))) void*)l, 16, 0, 0);
}

// ============================================================================
// prep A: windowed frames -> bf16, padded to M_PAD rows. grid 15000 x 256
// ============================================================================
__global__ __launch_bounds__(256) void prep_a(
    const float* __restrict__ sig, const float* __restrict__ wnd,
    ushort* __restrict__ A)
{
    int idx = blockIdx.x * 256 + threadIdx.x;     // < M_PAD * 200
    int row = idx / 200;
    int c4  = idx - row * 200;
    uint2 p;
    if (row < M_TOTAL) {
        int b = row / FRAMES;
        int f = row - b * FRAMES;
        const float4 s = *(const float4*)(sig + (size_t)b * SIGLEN + f * FSTEP + c4 * 4);
        const float4 w = *(const float4*)(wnd + c4 * 4);
        p.x = f2bf_pair(s.x * w.x, s.y * w.y);
        p.y = f2bf_pair(s.z * w.z, s.w * w.w);
    } else {
        p = make_uint2(0u, 0u);
    }
    *(uint2*)(A + (size_t)row * K_TOTAL + c4 * 4) = p;
}

// ============================================================================
// prep B: interleaved re/im DFT rows -> bf16, padded to N_PAD. grid 700 x 256
// row j (= output column j): j even -> dft_cos[j/2], j odd -> dft_sin[j/2]
// ============================================================================
__global__ __launch_bounds__(256) void prep_b(
    const float* __restrict__ dcos, const float* __restrict__ dsin,
    ushort* __restrict__ B)
{
    int idx = blockIdx.x * 256 + threadIdx.x;     // < N_PAD * 200
    int j  = idx / 200;
    int c4 = idx - j * 200;
    uint2 p;
    if (j < NOUT) {
        const float* src = ((j & 1) ? dsin : dcos) + (size_t)(j >> 1) * K_TOTAL;
        const float4 s = *(const float4*)(src + c4 * 4);
        p.x = f2bf_pair(s.x, s.y);
        p.y = f2bf_pair(s.z, s.w);
    } else {
        p = make_uint2(0u, 0u);
    }
    *(uint2*)(B + (size_t)j * K_TOTAL + c4 * 4) = p;
}

// ============================================================================
// GEMM: C[19152 x 802] = A[M,800] * B^T[802,800], m97 structure
// linear LDS [128][32] bf16 (64B row stride -> 2-way alias, free),
// global_load_lds width 16, 16x16x32 bf16 MFMA, 4 waves (2x2), 4x4 acc/wave
// ============================================================================
__global__ __launch_bounds__(256) void stft_gemm_bf16(
    const ushort* __restrict__ A, const ushort* __restrict__ B,
    float* __restrict__ out)
{
    __shared__ ushort As[BM * BK];   // 8 KiB
    __shared__ ushort Bs[BN * BK];   // 8 KiB

    const int tid = threadIdx.x;

    // bijective XCD swizzle (m204): nwg=1050, q=131, r=2
    const int orig = blockIdx.x;
    const int xcd  = orig & 7;
    const int lid  = orig >> 3;
    const int bid  = (xcd < 2 ? xcd * 132 : 264 + (xcd - 2) * 131) + lid;

    const int mt = bid / NTILES_N;
    const int nt = bid - mt * NTILES_N;
    const int m0 = mt * BM;
    const int j0 = nt * BN;

    const int wave = tid >> 6;
    const int lane = tid & 63;
    const int wm   = wave >> 1;
    const int wn   = wave & 1;
    const int lr   = lane & 15;
    const int lg   = lane >> 4;

    // staging: thread t, call c covers tile row c*64 + (t>>2), col (t&3)*8 elems
    const int sRow = tid >> 2;
    const int sCol = (tid & 3) * 8;
    const ushort* aSrc0 = A + (size_t)(m0 + sRow) * K_TOTAL + sCol;
    const ushort* aSrc1 = aSrc0 + (size_t)64 * K_TOTAL;
    const ushort* bSrc0 = B + (size_t)(j0 + sRow) * K_TOTAL + sCol;
    const ushort* bSrc1 = bSrc0 + (size_t)64 * K_TOTAL;
    // wave-uniform LDS bases (bytes): call c -> +c*4096, wave -> +wave*1024
    char* aDst0 = (char*)As + wave * 1024;
    char* aDst1 = (char*)As + 4096 + wave * 1024;
    char* bDst0 = (char*)Bs + wave * 1024;
    char* bDst1 = (char*)Bs + 4096 + wave * 1024;

    f32x4 acc[4][4];
    #pragma unroll
    for (int i = 0; i < 4; ++i)
        #pragma unroll
        for (int jj = 0; jj < 4; ++jj)
            acc[i][jj] = (f32x4){0.f, 0.f, 0.f, 0.f};

    for (int k0 = 0; k0 < K_TOTAL; k0 += BK) {
        gload_lds16(aSrc0 + k0, aDst0);
        gload_lds16(aSrc1 + k0, aDst1);
        gload_lds16(bSrc0 + k0, bDst0);
        gload_lds16(bSrc1 + k0, bDst1);
        __syncthreads();   // drains vmcnt -> LDS tiles ready

        bf16x8 a[4], b[4];
        #pragma unroll
        for (int i = 0; i < 4; ++i)
            a[i] = *(const bf16x8*)&As[(wm * 64 + i * 16 + lr) * BK + lg * 8];
        #pragma unroll
        for (int i = 0; i < 4; ++i)
            b[i] = *(const bf16x8*)&Bs[(wn * 64 + i * 16 + lr) * BK + lg * 8];
        #pragma unroll
        for (int i = 0; i < 4; ++i)
            #pragma unroll
            for (int jj = 0; jj < 4; ++jj)
                acc[i][jj] = __builtin_amdgcn_mfma_f32_16x16x32_bf16(a[i], b[jj], acc[i][jj], 0, 0, 0);

        __syncthreads();
    }

    // epilogue: C/D layout col=lane&15, row=4*(lane>>4)+reg
    const int mb = m0 + wm * 64;
    const int jb = j0 + wn * 64;
    #pragma unroll
    for (int i = 0; i < 4; ++i) {
        #pragma unroll
        for (int jj = 0; jj < 4; ++jj) {
            int col = jb + jj * 16 + lr;
            if (col >= NOUT) continue;
            #pragma unroll
            for (int r = 0; r < 4; ++r) {
                int row = mb + i * 16 + lg * 4 + r;
                if (row < M_TOTAL)
                    out[(size_t)row * NOUT + col] = acc[i][jj][r];
            }
        }
    }
}

// ============================================================================
// fallback (R1 kernel): in-kernel gather+window+convert, no workspace needed
// ============================================================================
#define LDSS 40
__global__ __launch_bounds__(256) void stft_gemm_fb(
    const float* __restrict__ sig, const float* __restrict__ wnd,
    const float* __restrict__ dcos, const float* __restrict__ dsin,
    float* __restrict__ out)
{
    __shared__ ushort As[BM * LDSS];
    __shared__ ushort Bs[BN * LDSS];
    __shared__ int rowBase[BM];

    const int tid = threadIdx.x;
    const int bid = blockIdx.x;
    const int mt  = bid / NTILES_N;
    const int nt  = bid - mt * NTILES_N;
    const int m0  = mt * BM;
    const int j0  = nt * BN;

    if (tid < BM) {
        int m = m0 + tid;
        int v = -1;
        if (m < M_TOTAL) {
            int b  = m / FRAMES;
            int fl = m - b * FRAMES;
            v = b * SIGLEN + fl * FSTEP;
        }
        rowBase[tid] = v;
    }

    const int rS = tid >> 1;
    const int hS = tid & 1;

    const float* bRow = nullptr;
    {
        int j = j0 + rS;
        if (j < NOUT) {
            const float* srcm = (j & 1) ? dsin : dcos;
            bRow = srcm + (size_t)(j >> 1) * K_TOTAL;
        }
    }

    const int lane = tid & 63;
    const int wave = tid >> 6;
    const int wm   = wave >> 1;
    const int wn   = wave & 1;
    const int lr   = lane & 15;
    const int lg   = lane >> 4;

    f32x4 acc[4][4];
    #pragma unroll
    for (int i = 0; i < 4; ++i)
        #pragma unroll
        for (int jj = 0; jj < 4; ++jj)
            acc[i][jj] = (f32x4){0.f, 0.f, 0.f, 0.f};

    __syncthreads();

    for (int k0 = 0; k0 < K_TOTAL; k0 += BK) {
        {
            int base = rowBase[rS];
            float4 f0, f1, f2, f3;
            if (base >= 0) {
                const float4* sp = (const float4*)(sig + base + k0 + hS * 16);
                f0 = sp[0]; f1 = sp[1]; f2 = sp[2]; f3 = sp[3];
            } else {
                f0 = make_float4(0.f,0.f,0.f,0.f); f1 = f0; f2 = f0; f3 = f0;
            }
            const float4* wp = (const float4*)(wnd + k0 + hS * 16);
            float4 w0 = wp[0], w1 = wp[1], w2 = wp[2], w3 = wp[3];
            uint4 p0, p1;
            p0.x = f2bf_pair(f0.x * w0.x, f0.y * w0.y);
            p0.y = f2bf_pair(f0.z * w0.z, f0.w * w0.w);
            p0.z = f2bf_pair(f1.x * w1.x, f1.y * w1.y);
            p0.w = f2bf_pair(f1.z * w1.z, f1.w * w1.w);
            p1.x = f2bf_pair(f2.x * w2.x, f2.y * w2.y);
            p1.y = f2bf_pair(f2.z * w2.z, f2.w * w2.w);
            p1.z = f2bf_pair(f3.x * w3.x, f3.y * w3.y);
            p1.w = f2bf_pair(f3.z * w3.z, f3.w * w3.w);
            uint4* dst = (uint4*)&As[rS * LDSS + hS * 16];
            dst[0] = p0; dst[1] = p1;
        }
        {
            uint4 p0, p1;
            if (bRow) {
                const float4* sp = (const float4*)(bRow + k0 + hS * 16);
                float4 f0 = sp[0], f1 = sp[1], f2 = sp[2], f3 = sp[3];
                p0.x = f2bf_pair(f0.x, f0.y);
                p0.y = f2bf_pair(f0.z, f0.w);
                p0.z = f2bf_pair(f1.x, f1.y);
                p0.w = f2bf_pair(f1.z, f1.w);
                p1.x = f2bf_pair(f2.x, f2.y);
                p1.y = f2bf_pair(f2.z, f2.w);
                p1.z = f2bf_pair(f3.x, f3.y);
                p1.w = f2bf_pair(f3.z, f3.w);
            } else {
                p0 = make_uint4(0u,0u,0u,0u); p1 = p0;
            }
            uint4* dst = (uint4*)&Bs[rS * LDSS + hS * 16];
            dst[0] = p0; dst[1] = p1;
        }
        __syncthreads();

        bf16x8 a[4], b[4];
        #pragma unroll
        for (int i = 0; i < 4; ++i)
            a[i] = *(const bf16x8*)&As[(wm * 64 + i * 16 + lr) * LDSS + lg * 8];
        #pragma unroll
        for (int i = 0; i < 4; ++i)
            b[i] = *(const bf16x8*)&Bs[(wn * 64 + i * 16 + lr) * LDSS + lg * 8];
        #pragma unroll
        for (int i = 0; i < 4; ++i)
            #pragma unroll
            for (int jj = 0; jj < 4; ++jj)
                acc[i][jj] = __builtin_amdgcn_mfma_f32_16x16x32_bf16(a[i], b[jj], acc[i][jj], 0, 0, 0);

        __syncthreads();
    }

    const int mb = m0 + wm * 64;
    const int jb = j0 + wn * 64;
    #pragma unroll
    for (int i = 0; i < 4; ++i) {
        #pragma unroll
        for (int jj = 0; jj < 4; ++jj) {
            int col = jb + jj * 16 + lr;
            if (col >= NOUT) continue;
            #pragma unroll
            for (int r = 0; r < 4; ++r) {
                int row = mb + i * 16 + lg * 4 + r;
                if (row < M_TOTAL)
                    out[(size_t)row * NOUT + col] = acc[i][jj][r];
            }
        }
    }
}

extern "C" void kernel_launch(void* const* d_in, const int* in_sizes, int n_in,
                              void* d_out, int out_size, void* d_ws, size_t ws_size,
                              hipStream_t stream) {
    const float* sig  = (const float*)d_in[0];
    const float* wnd  = (const float*)d_in[1];
    const float* dcos = (const float*)d_in[2];
    const float* dsin = (const float*)d_in[3];
    float* out = (float*)d_out;

    if (ws_size >= WS_NEEDED && d_ws != nullptr) {
        ushort* Aws = (ushort*)d_ws;
        ushort* Bws = Aws + A_WS_ELEMS;
        prep_a<<<dim3(M_PAD * 200 / 256), dim3(256), 0, stream>>>(sig, wnd, Aws);
        prep_b<<<dim3(N_PAD * 200 / 256), dim3(256), 0, stream>>>(dcos, dsin, Bws);
        stft_gemm_bf16<<<dim3(NWG), dim3(256), 0, stream>>>(Aws, Bws, out);
    } else {
        stft_gemm_fb<<<dim3(NWG), dim3(256), 0, stream>>>(sig, wnd, dcos, dsin, out);
    }
}

// Round 4
// 66.184 us; speedup vs baseline: 1.9953x; 1.2473x over previous
//
#include <hip/hip_runtime.h>
#include <hip/hip_bf16.h>

// ---- problem constants ----
#define NBATCH   16
#define SIGLEN   240000
#define FRAMES   1197                 // (240000-800)/200 + 1
#define M_TOTAL  (NBATCH * FRAMES)    // 19152
#define K_TOTAL  800
#define NBINS    401
#define NOUT     (2 * NBINS)          // 802, interleaved re/im
#define FSTEP    200

// ---- GEMM tiling ----
#define BM 128
#define BN 128
#define BK 32
#define NT (K_TOTAL / BK)             // 25 K-steps
#define NTILES_N 7                    // ceil(802/128)
#define NTILES_M 150                  // ceil(19152/128)
#define NWG      (NTILES_M * NTILES_N) // 1050
#define N_PAD    (NTILES_N * BN)      // 896

#define SIG_ELEMS ((size_t)NBATCH * SIGLEN)           // 3,840,000 bf16
#define B_WS_ELEMS ((size_t)N_PAD * K_TOTAL)          // 716,800 bf16
#define WS_NEEDED  ((SIG_ELEMS + B_WS_ELEMS) * 2)     // ~9.1 MB

// LDS geometry (bytes): one tile = 128 rows x 32 cols x 2B = 8192
#define TILE_B   8192
#define HALF_B   4096

typedef float  f32x4  __attribute__((ext_vector_type(4)));
typedef __bf16 bf16x8 __attribute__((ext_vector_type(8)));

static __device__ __forceinline__ unsigned f2bf_pair(float lo, float hi) {
    // RNE f32->bf16, packed pair
    union { float f; unsigned u; } a, b;
    a.f = lo; b.f = hi;
    unsigned ua = (a.u + 0x7fffu + ((a.u >> 16) & 1u)) >> 16;
    unsigned ub = (b.u + 0x7fffu + ((b.u >> 16) & 1u)) >> 16;
    return ua | (ub << 16);
}

static __device__ __forceinline__ void gload_lds16(const void* g, void* l) {
    // async global->LDS: 16B per lane; LDS dest = wave-uniform base + lane*16,
    // global source is PER-LANE (enables the frame gather).
    __builtin_amdgcn_global_load_lds(
        (const __attribute__((address_space(1))) void*)g,
        (__attribute__((address_space(3))) void*)l, 16, 0, 0);
}

// ============================================================================
// prep: signal f32 -> bf16 (8 elems/thread). grid 1875 x 256
// ============================================================================
__global__ __launch_bounds__(256) void prep_sig(
    const float* __restrict__ sig, ushort* __restrict__ sbf)
{
    size_t i8 = ((size_t)blockIdx.x * 256 + threadIdx.x) * 8;
    const float4 s0 = *(const float4*)(sig + i8);
    const float4 s1 = *(const float4*)(sig + i8 + 4);
    uint4 p;
    p.x = f2bf_pair(s0.x, s0.y);
    p.y = f2bf_pair(s0.z, s0.w);
    p.z = f2bf_pair(s1.x, s1.y);
    p.w = f2bf_pair(s1.z, s1.w);
    *(uint4*)(sbf + i8) = p;
}

// ============================================================================
// prep: windowed interleaved DFT -> bf16, padded to N_PAD rows. grid 350 x 256
// row j (= output column j): j even -> w[n]*dft_cos[j/2][n], j odd -> sin
// ============================================================================
__global__ __launch_bounds__(256) void prep_bw(
    const float* __restrict__ dcos, const float* __restrict__ dsin,
    const float* __restrict__ wnd, ushort* __restrict__ B)
{
    int idx = blockIdx.x * 256 + threadIdx.x;     // < N_PAD * 100
    int j  = idx / 100;
    int c8 = (idx - j * 100) * 8;
    uint4 p;
    if (j < NOUT) {
        const float* src = ((j & 1) ? dsin : dcos) + (size_t)(j >> 1) * K_TOTAL + c8;
        const float4 s0 = *(const float4*)(src);
        const float4 s1 = *(const float4*)(src + 4);
        const float4 w0 = *(const float4*)(wnd + c8);
        const float4 w1 = *(const float4*)(wnd + c8 + 4);
        p.x = f2bf_pair(s0.x * w0.x, s0.y * w0.y);
        p.y = f2bf_pair(s0.z * w0.z, s0.w * w0.w);
        p.z = f2bf_pair(s1.x * w1.x, s1.y * w1.y);
        p.w = f2bf_pair(s1.z * w1.z, s1.w * w1.w);
    } else {
        p = make_uint4(0u, 0u, 0u, 0u);
    }
    *(uint4*)(B + (size_t)j * K_TOTAL + c8) = p;
}

// ============================================================================
// GEMM: C[19152 x 802] = frames[M,800] * Bw^T[802,800]
// A gathered directly from bf16 signal (per-lane gload_lds source addrs);
// double-buffered LDS, 1 barrier/iter, loads overlap MFMA (T3 2-phase).
// ============================================================================
__global__ __launch_bounds__(256) void stft_gemm_bf16(
    const ushort* __restrict__ sigbf, const ushort* __restrict__ B,
    float* __restrict__ out)
{
    __shared__ ushort As[2][BM * BK];   // 2 x 8192 B
    __shared__ ushort Bs[2][BN * BK];   // 2 x 8192 B

    const int tid = threadIdx.x;

    // bijective XCD swizzle (m204): nwg=1050, q=131, r=2
    const int orig = blockIdx.x;
    const int xcd  = orig & 7;
    const int lid  = orig >> 3;
    const int bid  = (xcd < 2 ? xcd * 132 : 264 + (xcd - 2) * 131) + lid;

    const int mt = bid / NTILES_N;
    const int nt = bid - mt * NTILES_N;
    const int m0 = mt * BM;
    const int j0 = nt * BN;

    const int wave = tid >> 6;
    const int lane = tid & 63;
    const int wm   = wave >> 1;
    const int wn   = wave & 1;
    const int lr   = lane & 15;
    const int lg   = lane >> 4;

    // staging: thread t covers tile row (t>>2) [+64], col (t&3)*8 elems
    const int sRow = tid >> 2;
    const int sCol = (tid & 3) * 8;

    // A source: gather from signal; frame rows are contiguous signal slices
    int m1 = m0 + sRow;          if (m1 >= M_TOTAL) m1 = M_TOTAL - 1;
    int m2 = m0 + sRow + 64;     if (m2 >= M_TOTAL) m2 = M_TOTAL - 1;
    const int b1 = m1 / FRAMES, f1 = m1 - b1 * FRAMES;
    const int b2 = m2 / FRAMES, f2 = m2 - b2 * FRAMES;
    const ushort* aS0 = sigbf + (size_t)b1 * SIGLEN + f1 * FSTEP + sCol;
    const ushort* aS1 = sigbf + (size_t)b2 * SIGLEN + f2 * FSTEP + sCol;
    const ushort* bS0 = B + (size_t)(j0 + sRow) * K_TOTAL + sCol;
    const ushort* bS1 = bS0 + (size_t)64 * K_TOTAL;

    // wave-uniform LDS dest bases (HW adds lane*16).
    // tile layout: row-major [128][32] bf16; thread tid's 16B lands at byte
    // tid*16 = wave*1024 + lane*16; rows 64-127 start at +4096.
    char* aD = (char*)&As[0][0] + wave * 1024;
    char* bD = (char*)&Bs[0][0] + wave * 1024;

#define STAGE(c, kofs) do {                                      \
        gload_lds16(aS0 + (kofs), aD + (c) * TILE_B);            \
        gload_lds16(aS1 + (kofs), aD + (c) * TILE_B + HALF_B);   \
        gload_lds16(bS0 + (kofs), bD + (c) * TILE_B);            \
        gload_lds16(bS1 + (kofs), bD + (c) * TILE_B + HALF_B);   \
    } while (0)

    f32x4 acc[4][4];
    #pragma unroll
    for (int i = 0; i < 4; ++i)
        #pragma unroll
        for (int jj = 0; jj < 4; ++jj)
            acc[i][jj] = (f32x4){0.f, 0.f, 0.f, 0.f};

    // prologue: stage tile 0 into buf 0
    STAGE(0, 0);
    __syncthreads();   // drains vmcnt -> buf0 ready

    int cur = 0;
    for (int t = 0; t < NT; ++t) {
        // issue next tile's loads early — they fly under this tile's compute
        if (t + 1 < NT) STAGE(cur ^ 1, (t + 1) * BK);

        bf16x8 a[4], b[4];
        #pragma unroll
        for (int i = 0; i < 4; ++i)
            a[i] = *(const bf16x8*)&As[cur][(wm * 64 + i * 16 + lr) * BK + lg * 8];
        #pragma unroll
        for (int i = 0; i < 4; ++i)
            b[i] = *(const bf16x8*)&Bs[cur][(wn * 64 + i * 16 + lr) * BK + lg * 8];

        __builtin_amdgcn_s_setprio(1);
        #pragma unroll
        for (int i = 0; i < 4; ++i)
            #pragma unroll
            for (int jj = 0; jj < 4; ++jj)
                acc[i][jj] = __builtin_amdgcn_mfma_f32_16x16x32_bf16(a[i], b[jj], acc[i][jj], 0, 0, 0);
        __builtin_amdgcn_s_setprio(0);

        __syncthreads();   // drains vmcnt -> next buf ready; reads of cur done
        cur ^= 1;
    }
#undef STAGE

    // epilogue: C/D layout col=lane&15, row=4*(lane>>4)+reg
    const int mb = m0 + wm * 64;
    const int jb = j0 + wn * 64;
    #pragma unroll
    for (int i = 0; i < 4; ++i) {
        #pragma unroll
        for (int jj = 0; jj < 4; ++jj) {
            int col = jb + jj * 16 + lr;
            if (col >= NOUT) continue;
            #pragma unroll
            for (int r = 0; r < 4; ++r) {
                int row = mb + i * 16 + lg * 4 + r;
                if (row < M_TOTAL)
                    out[(size_t)row * NOUT + col] = acc[i][jj][r];
            }
        }
    }
}

// ============================================================================
// fallback (no workspace): in-kernel gather+window+convert
// ============================================================================
#define LDSS 40
__global__ __launch_bounds__(256) void stft_gemm_fb(
    const float* __restrict__ sig, const float* __restrict__ wnd,
    const float* __restrict__ dcos, const float* __restrict__ dsin,
    float* __restrict__ out)
{
    __shared__ ushort As[BM * LDSS];
    __shared__ ushort Bs[BN * LDSS];
    __shared__ int rowBase[BM];

    const int tid = threadIdx.x;
    const int bid = blockIdx.x;
    const int mt  = bid / NTILES_N;
    const int nt  = bid - mt * NTILES_N;
    const int m0  = mt * BM;
    const int j0  = nt * BN;

    if (tid < BM) {
        int m = m0 + tid;
        int v = -1;
        if (m < M_TOTAL) {
            int b  = m / FRAMES;
            int fl = m - b * FRAMES;
            v = b * SIGLEN + fl * FSTEP;
        }
        rowBase[tid] = v;
    }

    const int rS = tid >> 1;
    const int hS = tid & 1;

    const float* bRow = nullptr;
    {
        int j = j0 + rS;
        if (j < NOUT) {
            const float* srcm = (j & 1) ? dsin : dcos;
            bRow = srcm + (size_t)(j >> 1) * K_TOTAL;
        }
    }

    const int lane = tid & 63;
    const int wave = tid >> 6;
    const int wm   = wave >> 1;
    const int wn   = wave & 1;
    const int lr   = lane & 15;
    const int lg   = lane >> 4;

    f32x4 acc[4][4];
    #pragma unroll
    for (int i = 0; i < 4; ++i)
        #pragma unroll
        for (int jj = 0; jj < 4; ++jj)
            acc[i][jj] = (f32x4){0.f, 0.f, 0.f, 0.f};

    __syncthreads();

    for (int k0 = 0; k0 < K_TOTAL; k0 += BK) {
        {
            int base = rowBase[rS];
            float4 f0, f1, f2, f3;
            if (base >= 0) {
                const float4* sp = (const float4*)(sig + base + k0 + hS * 16);
                f0 = sp[0]; f1 = sp[1]; f2 = sp[2]; f3 = sp[3];
            } else {
                f0 = make_float4(0.f,0.f,0.f,0.f); f1 = f0; f2 = f0; f3 = f0;
            }
            const float4* wp = (const float4*)(wnd + k0 + hS * 16);
            float4 w0 = wp[0], w1 = wp[1], w2 = wp[2], w3 = wp[3];
            uint4 p0, p1;
            p0.x = f2bf_pair(f0.x * w0.x, f0.y * w0.y);
            p0.y = f2bf_pair(f0.z * w0.z, f0.w * w0.w);
            p0.z = f2bf_pair(f1.x * w1.x, f1.y * w1.y);
            p0.w = f2bf_pair(f1.z * w1.z, f1.w * w1.w);
            p1.x = f2bf_pair(f2.x * w2.x, f2.y * w2.y);
            p1.y = f2bf_pair(f2.z * w2.z, f2.w * w2.w);
            p1.z = f2bf_pair(f3.x * w3.x, f3.y * w3.y);
            p1.w = f2bf_pair(f3.z * w3.z, f3.w * w3.w);
            uint4* dst = (uint4*)&As[rS * LDSS + hS * 16];
            dst[0] = p0; dst[1] = p1;
        }
        {
            uint4 p0, p1;
            if (bRow) {
                const float4* sp = (const float4*)(bRow + k0 + hS * 16);
                float4 f0 = sp[0], f1 = sp[1], f2 = sp[2], f3 = sp[3];
                p0.x = f2bf_pair(f0.x, f0.y);
                p0.y = f2bf_pair(f0.z, f0.w);
                p0.z = f2bf_pair(f1.x, f1.y);
                p0.w = f2bf_pair(f1.z, f1.w);
                p1.x = f2bf_pair(f2.x, f2.y);
                p1.y = f2bf_pair(f2.z, f2.w);
                p1.z = f2bf_pair(f3.x, f3.y);
                p1.w = f2bf_pair(f3.z, f3.w);
            } else {
                p0 = make_uint4(0u,0u,0u,0u); p1 = p0;
            }
            uint4* dst = (uint4*)&Bs[rS * LDSS + hS * 16];
            dst[0] = p0; dst[1] = p1;
        }
        __syncthreads();

        bf16x8 a[4], b[4];
        #pragma unroll
        for (int i = 0; i < 4; ++i)
            a[i] = *(const bf16x8*)&As[(wm * 64 + i * 16 + lr) * LDSS + lg * 8];
        #pragma unroll
        for (int i = 0; i < 4; ++i)
            b[i] = *(const bf16x8*)&Bs[(wn * 64 + i * 16 + lr) * LDSS + lg * 8];
        #pragma unroll
        for (int i = 0; i < 4; ++i)
            #pragma unroll
            for (int jj = 0; jj < 4; ++jj)
                acc[i][jj] = __builtin_amdgcn_mfma_f32_16x16x32_bf16(a[i], b[jj], acc[i][jj], 0, 0, 0);

        __syncthreads();
    }

    const int mb = m0 + wm * 64;
    const int jb = j0 + wn * 64;
    #pragma unroll
    for (int i = 0; i < 4; ++i) {
        #pragma unroll
        for (int jj = 0; jj < 4; ++jj) {
            int col = jb + jj * 16 + lr;
            if (col >= NOUT) continue;
            #pragma unroll
            for (int r = 0; r < 4; ++r) {
                int row = mb + i * 16 + lg * 4 + r;
                if (row < M_TOTAL)
                    out[(size_t)row * NOUT + col] = acc[i][jj][r];
            }
        }
    }
}

extern "C" void kernel_launch(void* const* d_in, const int* in_sizes, int n_in,
                              void* d_out, int out_size, void* d_ws, size_t ws_size,
                              hipStream_t stream) {
    const float* sig  = (const float*)d_in[0];
    const float* wnd  = (const float*)d_in[1];
    const float* dcos = (const float*)d_in[2];
    const float* dsin = (const float*)d_in[3];
    float* out = (float*)d_out;

    if (ws_size >= WS_NEEDED && d_ws != nullptr) {
        ushort* sbf = (ushort*)d_ws;
        ushort* Bws = sbf + SIG_ELEMS;
        prep_sig<<<dim3(SIG_ELEMS / 8 / 256), dim3(256), 0, stream>>>(sig, sbf);
        prep_bw<<<dim3(N_PAD * 100 / 256), dim3(256), 0, stream>>>(dcos, dsin, wnd, Bws);
        stft_gemm_bf16<<<dim3(NWG), dim3(256), 0, stream>>>(sbf, Bws, out);
    } else {
        stft_gemm_fb<<<dim3(NWG), dim3(256), 0, stream>>>(sig, wnd, dcos, dsin, out);
    }
}